// Round 5
// baseline (348.886 us; speedup 1.0000x reference)
//
#include <hip/hip_runtime.h>
#include <stdint.h>

#define D 2048
#define V 4096
#define TINYF 1.17549435e-38f
#define NINF (-__builtin_huge_valf())

// ---------------- threefry (JAX partitionable scheme, verified exact R1/R3) --------
__device__ __forceinline__ void tf_block(uint32_t k0, uint32_t k1, uint32_t x0, uint32_t x1,
                                         uint32_t& o0, uint32_t& o1) {
  uint32_t ks2 = k0 ^ k1 ^ 0x1BD11BDAu;
  uint32_t ks[3] = {k0, k1, ks2};
  x0 += k0; x1 += k1;
  const uint32_t rotA[4] = {13u, 15u, 26u, 6u};
  const uint32_t rotB[4] = {17u, 29u, 16u, 24u};
#pragma unroll
  for (int i = 0; i < 5; ++i) {
    const uint32_t* rot = (i & 1) ? rotB : rotA;
#pragma unroll
    for (int j = 0; j < 4; ++j) {
      uint32_t r = rot[j];
      x0 += x1;
      x1 = (x1 << r) | (x1 >> (32u - r));
      x1 ^= x0;
    }
    x0 += ks[(i + 1) % 3];
    x1 += ks[(i + 2) % 3] + (uint32_t)(i + 1);
  }
  o0 = x0; o1 = x1;
}

__device__ __forceinline__ float gumbel_at(uint32_t k1, uint32_t k2, int i) {
  uint32_t o0, o1;
  tf_block(k1, k2, 0u, (uint32_t)i, o0, o1);
  uint32_t bits = o0 ^ o1;
  float u = __uint_as_float((bits >> 9) | 0x3F800000u) - 1.0f;
  u = fmaxf(TINYF, u + TINYF);
  return -logf(-logf(u));
}

// ---------------- load helpers -----------------------------------------------------
typedef float vfloat4 __attribute__((ext_vector_type(4)));

__device__ __forceinline__ float4 ntload4(const float4* p) {
  vfloat4 v = __builtin_nontemporal_load((const vfloat4*)p);
  return make_float4(v.x, v.y, v.z, v.w);
}

__device__ __forceinline__ void load8w(const uint16_t* __restrict__ p, float* w) {
  uint4 u = *(const uint4*)p;
  w[0] = __uint_as_float(u.x << 16); w[1] = __uint_as_float(u.x & 0xFFFF0000u);
  w[2] = __uint_as_float(u.y << 16); w[3] = __uint_as_float(u.y & 0xFFFF0000u);
  w[4] = __uint_as_float(u.z << 16); w[5] = __uint_as_float(u.z & 0xFFFF0000u);
  w[6] = __uint_as_float(u.w << 16); w[7] = __uint_as_float(u.w & 0xFFFF0000u);
}

__device__ __forceinline__ void load8w(const float* __restrict__ p, float* w) {
  *(float4*)w = *(const float4*)p;
  *(float4*)(w + 4) = *(const float4*)(p + 4);
}

// row·xs for LDS-staged xs (f32 / bf16 weight rows) — identical math to R3
__device__ __forceinline__ float row_dot(const float* __restrict__ row,
                                         const float* __restrict__ xs, int lane) {
  float a = 0.f;
#pragma unroll
  for (int k = lane * 4; k < D; k += 256) {
    float4 w = *(const float4*)(row + k);
    float4 x = *(const float4*)(xs + k);
    a += w.x * x.x + w.y * x.y + w.z * x.z + w.w * x.w;
  }
  return a;
}

__device__ __forceinline__ float row_dot(const uint16_t* __restrict__ row,
                                         const float* __restrict__ xs, int lane) {
  float a = 0.f;
#pragma unroll
  for (int k = lane * 8; k < D; k += 512) {
    uint4 u = *(const uint4*)(row + k);
    float4 x0 = *(const float4*)(xs + k);
    float4 x1 = *(const float4*)(xs + k + 4);
    a += __uint_as_float(u.x << 16) * x0.x + __uint_as_float(u.x & 0xFFFF0000u) * x0.y;
    a += __uint_as_float(u.y << 16) * x0.z + __uint_as_float(u.y & 0xFFFF0000u) * x0.w;
    a += __uint_as_float(u.z << 16) * x1.x + __uint_as_float(u.z & 0xFFFF0000u) * x1.y;
    a += __uint_as_float(u.w << 16) * x1.z + __uint_as_float(u.w & 0xFFFF0000u) * x1.w;
  }
  return a;
}

// ---------------- f32 -> bf16 (RNE) weight pack -------------------------------------
__global__ void convert_k(const float* __restrict__ wih, const float* __restrict__ whh,
                          const float* __restrict__ l1, const float* __restrict__ l2,
                          uint16_t* __restrict__ dwih, uint16_t* __restrict__ dwhh,
                          uint16_t* __restrict__ dl1, uint16_t* __restrict__ dl2) {
  size_t gid = (size_t)blockIdx.x * 256 + threadIdx.x;  // 8-float chunk id
  const size_t C1 = (size_t)4 * D * D / 8;
  const size_t C2 = 2 * C1;
  const size_t C3 = C2 + (size_t)D * D / 8;
  const size_t C4 = C3 + (size_t)D * D / 8;
  const float* src; uint16_t* dst; size_t off;
  if (gid < C1)      { src = wih; dst = dwih; off = gid; }
  else if (gid < C2) { src = whh; dst = dwhh; off = gid - C1; }
  else if (gid < C3) { src = l1;  dst = dl1;  off = gid - C2; }
  else if (gid < C4) { src = l2;  dst = dl2;  off = gid - C3; }
  else return;
  const float4* s = (const float4*)(src + off * 8);
  float4 a = ntload4(s), b = ntload4(s + 1);
  float v[8] = {a.x, a.y, a.z, a.w, b.x, b.y, b.z, b.w};
  uint32_t r[8];
#pragma unroll
  for (int t = 0; t < 8; ++t) {
    uint32_t x = __float_as_uint(v[t]);
    x = x + 0x7FFFu + ((x >> 16) & 1u);   // round-to-nearest-even
    r[t] = x >> 16;
  }
  uint4 o;
  o.x = r[0] | (r[1] << 16);
  o.y = r[2] | (r[3] << 16);
  o.z = r[4] | (r[5] << 16);
  o.w = r[6] | (r[7] << 16);
  *(uint4*)(dst + off * 8) = o;
}

// ---------------- LSTM cell (first cell of each layer + final): R3-proven -----------
template <typename WT>
__global__ void lstm_cell_k(const WT* __restrict__ w_ih, const WT* __restrict__ w_hh,
                            const float* __restrict__ b_ih, const float* __restrict__ b_hh,
                            const float* __restrict__ x_base, const int* __restrict__ x_idx,
                            const float* __restrict__ h_in, const float* __restrict__ c_in,
                            float* __restrict__ h_out, float* __restrict__ c_out,
                            float* __restrict__ c_copy) {
  __shared__ float xs[D];
  __shared__ float hs[D];
  int tid = threadIdx.x;
  const float* x = x_base;
  if (x_idx) x += (size_t)(*x_idx) * D;
  for (int i = tid; i < D; i += 256) { xs[i] = x[i]; hs[i] = h_in ? h_in[i] : 0.f; }
  __syncthreads();
  int wave = tid >> 6, lane = tid & 63;
  int j = blockIdx.x * 4 + wave;
  float gv[4];
#pragma unroll
  for (int m = 0; m < 4; ++m) {
    float a = row_dot(w_ih + (size_t)(m * D + j) * D, xs, lane)
            + row_dot(w_hh + (size_t)(m * D + j) * D, hs, lane);
#pragma unroll
    for (int off = 32; off > 0; off >>= 1) a += __shfl_down(a, off, 64);
    gv[m] = a + b_ih[m * D + j] + b_hh[m * D + j];
  }
  if (lane == 0) {
    float ig = 1.f / (1.f + expf(-gv[0]));
    float fg = 1.f / (1.f + expf(-gv[1]));
    float gg = tanhf(gv[2]);
    float og = 1.f / (1.f + expf(-gv[3]));
    float ci = c_in ? c_in[j] : 0.f;
    float cn = fg * ci + ig * gg;
    float hn = og * tanhf(cn);
    c_out[j] = cn;
    h_out[j] = hn;
    if (c_copy) c_copy[j] = cn;
  }
}

// ---------------- speculative 2nd-cell gate GEMV + lin1/lin2, one launch ------------
// blocks [0,512): for each of 4 gate rows j: g_hh = w_hh·h1 + b_ih + b_hh, and
//                 g_ih[t] = w_ih·all_c[t] for ALL skip candidates t (memory-bound:
//                 weights read once, NC FMA streams). No LDS: candidates reg-cached.
// blocks [512,1536): lin1 -> all_cw[layer], lin2 -> qb (R3 lin12 logic).
template <typename WT, int NC>
__global__ void spec_lin_k(const WT* __restrict__ w_ih, const WT* __restrict__ w_hh,
                           const float* __restrict__ b_ih, const float* __restrict__ b_hh,
                           const float* __restrict__ h1, const float* __restrict__ all_c,
                           const WT* __restrict__ l1w, const float* __restrict__ l1b,
                           const WT* __restrict__ l2w, const float* __restrict__ l2b,
                           const float* __restrict__ c1,
                           float* __restrict__ g_ih, float* __restrict__ g_hh,
                           float* __restrict__ cw_dst, float* __restrict__ qb) {
  __shared__ float xs[D];
  int tid = threadIdx.x;
  int wave = tid >> 6, lane = tid & 63;
  int b = blockIdx.x;
  if (b < 512) {
    int j = b * 4 + wave;
    float acc[4][NC + 1];
#pragma unroll
    for (int m = 0; m < 4; ++m)
#pragma unroll
      for (int t = 0; t < NC + 1; ++t) acc[m][t] = 0.f;
    for (int k = lane * 8; k < D; k += 512) {
      float xh[8];
      float xc[NC][8];
      *(float4*)xh       = *(const float4*)(h1 + k);
      *(float4*)(xh + 4) = *(const float4*)(h1 + k + 4);
#pragma unroll
      for (int t = 0; t < NC; ++t) {
        *(float4*)(xc[t])     = *(const float4*)(all_c + (size_t)t * D + k);
        *(float4*)(xc[t] + 4) = *(const float4*)(all_c + (size_t)t * D + k + 4);
      }
#pragma unroll
      for (int m = 0; m < 4; ++m) {
        float wi[8], wh[8];
        load8w(w_ih + (size_t)(m * D + j) * D + k, wi);
        load8w(w_hh + (size_t)(m * D + j) * D + k, wh);
#pragma unroll
        for (int e = 0; e < 8; ++e) acc[m][0] += wh[e] * xh[e];
#pragma unroll
        for (int t = 0; t < NC; ++t)
#pragma unroll
          for (int e = 0; e < 8; ++e) acc[m][1 + t] += wi[e] * xc[t][e];
      }
    }
#pragma unroll
    for (int m = 0; m < 4; ++m)
#pragma unroll
      for (int t = 0; t < NC + 1; ++t) {
        float a = acc[m][t];
#pragma unroll
        for (int o = 32; o > 0; o >>= 1) a += __shfl_down(a, o, 64);
        if (lane == 0) {
          if (t == 0) g_hh[m * D + j] = a + b_ih[m * D + j] + b_hh[m * D + j];
          else        g_ih[((size_t)(t - 1) * 4 + m) * D + j] = a;
        }
      }
  } else {
    for (int i = tid; i < D; i += 256) xs[i] = c1[i];
    __syncthreads();
    int b2 = b - 512;
    const WT* Wp; const float* bp; float* dst; int row;
    if (b2 < 512) { row = b2 * 4 + wave; Wp = l1w; bp = l1b; dst = cw_dst; }
    else          { row = (b2 - 512) * 4 + wave; Wp = l2w; bp = l2b; dst = qb; }
    float a = row_dot(Wp + (size_t)row * D, xs, lane);
#pragma unroll
    for (int o = 32; o > 0; o >>= 1) a += __shfl_down(a, o, 64);
    if (lane == 0) dst[row] = a + bp[row];
  }
}

// ---------------- fused: attn-sample (redundant per block) + gate select + c2/h2
//                  + decoder GEMV. 1024 blocks; block 0 writes h2/c2/outputs. --------
__global__ void dec_fused_k(const float* __restrict__ Wdec, const float* __restrict__ bdec,
                            const float* __restrict__ g_ih, const float* __restrict__ g_hh,
                            const float* __restrict__ c1,
                            const float* __restrict__ qb, const float* __restrict__ all_cw,
                            const float* __restrict__ lin3_w, const float* __restrict__ lin3_b,
                            int ncand, int step,
                            float* __restrict__ logits,
                            float* __restrict__ h2_out, float* __restrict__ c2_out,
                            float* __restrict__ out_arc, float* __restrict__ out_ent,
                            float* __restrict__ out_lp) {
  __shared__ float xs[D];
  __shared__ float red[16];
  __shared__ int s_sel;
  int tid = threadIdx.x, wave = tid >> 6, lane = tid & 63;
  // attention logits (each block redundantly; identical IEEE result in every block)
  for (int t = 0; t < ncand; ++t) {
    float s = 0.f;
    for (int k = tid; k < D; k += 256) s += tanhf(qb[k] + all_cw[(size_t)t * D + k]) * lin3_w[k];
#pragma unroll
    for (int o = 32; o > 0; o >>= 1) s += __shfl_down(s, o, 64);
    if (lane == 0) red[t * 4 + wave] = s;
  }
  __syncthreads();
  if (tid == 0) {
    float sl[4];
    for (int t = 0; t < ncand; ++t)
      sl[t] = red[t * 4] + red[t * 4 + 1] + red[t * 4 + 2] + red[t * 4 + 3] + lin3_b[0];
    uint32_t k1, k2; tf_block(0u, 42u, 0u, (uint32_t)step, k1, k2);
    float m = NINF;
    for (int i = 0; i < ncand; ++i) m = fmaxf(m, sl[i]);
    float S = 0.f, T = 0.f;
    for (int i = 0; i < ncand; ++i) { float e = expf(sl[i] - m); S += e; T += e * (sl[i] - m); }
    float L = logf(S);
    float bv = NINF; int bi = 0;
    for (int i = 0; i < ncand; ++i) {
      float sc = gumbel_at(k1, k2, i) + sl[i];
      if (sc > bv) { bv = sc; bi = i; }
    }
    s_sel = bi;
    if (blockIdx.x == 0) {
      *out_arc = (float)bi;
      *out_ent = L - T / S;
      *out_lp  = sl[bi] - m - L;
    }
  }
  __syncthreads();
  int sel = s_sel;
  const float* gi = g_ih + (size_t)sel * 4 * D;
  bool b0 = (blockIdx.x == 0);
  for (int j = tid; j < D; j += 256) {
    float gI = gi[j]         + g_hh[j];
    float gF = gi[D + j]     + g_hh[D + j];
    float gG = gi[2 * D + j] + g_hh[2 * D + j];
    float gO = gi[3 * D + j] + g_hh[3 * D + j];
    float ig = 1.f / (1.f + expf(-gI));
    float fg = 1.f / (1.f + expf(-gF));
    float gg = tanhf(gG);
    float og = 1.f / (1.f + expf(-gO));
    float cn = fg * c1[j] + ig * gg;
    xs[j] = cn;
    if (b0) { c2_out[j] = cn; h2_out[j] = og * tanhf(cn); }
  }
  __syncthreads();
  // decoder GEMV rows (nontemporal: dec_w is single-use)
  int row = blockIdx.x * 4 + wave;
  const float* wr = Wdec + (size_t)row * D;
  float a = 0.f;
#pragma unroll
  for (int k = lane * 4; k < D; k += 256) {
    float4 w = ntload4((const float4*)(wr + k));
    float4 x = *(const float4*)(xs + k);
    a += w.x * x.x + w.y * x.y + w.z * x.z + w.w * x.w;
  }
#pragma unroll
  for (int o = 32; o > 0; o >>= 1) a += __shfl_down(a, o, 64);
  if (lane == 0) logits[row] = a + bdec[row];
}

// ---------------- final decoder GEMV (plain) ----------------------------------------
__global__ void gemv_k(const float* __restrict__ W, const float* __restrict__ bias,
                       const float* __restrict__ c, float* __restrict__ y) {
  __shared__ float xs[D];
  int tid = threadIdx.x;
  for (int i = tid; i < D; i += 256) xs[i] = c[i];
  __syncthreads();
  int wave = tid >> 6, lane = tid & 63;
  int row = blockIdx.x * 4 + wave;
  const float* wr = W + (size_t)row * D;
  float a = 0.f;
#pragma unroll
  for (int k = lane * 4; k < D; k += 256) {
    float4 w = ntload4((const float4*)(wr + k));
    float4 x = *(const float4*)(xs + k);
    a += w.x * x.x + w.y * x.y + w.z * x.z + w.w * x.w;
  }
#pragma unroll
  for (int o = 32; o > 0; o >>= 1) a += __shfl_down(a, o, 64);
  if (lane == 0) y[row] = a + bias[row];
}

// ---------------- V=4096 sampler, one block of 1024 (R3-proven) ---------------------
__global__ void sample_k(const float* __restrict__ logits, int step,
                         float* __restrict__ out_arc, float* __restrict__ out_ent,
                         float* __restrict__ out_lp, int* __restrict__ sel_out) {
  __shared__ float red[1024];
  __shared__ int redi[1024];
  int tid = threadIdx.x;
  uint32_t k1, k2; tf_block(0u, 42u, 0u, (uint32_t)step, k1, k2);
  float xv[4];
  float m = NINF, bv = NINF; int bi = 1 << 30;
#pragma unroll
  for (int t = 0; t < 4; ++t) {
    int i = tid + t * 1024;
    float x = logits[i];
    xv[t] = x;
    m = fmaxf(m, x);
    float sc = gumbel_at(k1, k2, i) + x;
    if (sc > bv) { bv = sc; bi = i; }
  }
  red[tid] = m; __syncthreads();
  for (int st = 512; st > 0; st >>= 1) { if (tid < st) red[tid] = fmaxf(red[tid], red[tid + st]); __syncthreads(); }
  m = red[0]; __syncthreads();
  float S = 0.f, T = 0.f;
#pragma unroll
  for (int t = 0; t < 4; ++t) { float e = expf(xv[t] - m); S += e; T += e * (xv[t] - m); }
  red[tid] = S; __syncthreads();
  for (int st = 512; st > 0; st >>= 1) { if (tid < st) red[tid] += red[tid + st]; __syncthreads(); }
  S = red[0]; __syncthreads();
  red[tid] = T; __syncthreads();
  for (int st = 512; st > 0; st >>= 1) { if (tid < st) red[tid] += red[tid + st]; __syncthreads(); }
  T = red[0]; __syncthreads();
  red[tid] = bv; redi[tid] = bi; __syncthreads();
  for (int st = 512; st > 0; st >>= 1) {
    if (tid < st) {
      float ov = red[tid + st]; int oi = redi[tid + st];
      if (ov > red[tid] || (ov == red[tid] && oi < redi[tid])) { red[tid] = ov; redi[tid] = oi; }
    }
    __syncthreads();
  }
  if (tid == 0) {
    float L = logf(S);
    int idx = redi[0];
    *out_arc = (float)idx;
    *out_ent = L - T / S;
    *out_lp  = logits[idx] - m - L;
    *sel_out = idx;
  }
}

// ---------------- host-side orchestration ------------------------------------------
extern "C" void kernel_launch(void* const* d_in, const int* in_sizes, int n_in,
                              void* d_out, int out_size, void* d_ws, size_t ws_size,
                              hipStream_t stream) {
  const float* emb0   = (const float*)d_in[0];
  const float* w_ih   = (const float*)d_in[1];
  const float* w_hh   = (const float*)d_in[2];
  const float* b_ih   = (const float*)d_in[3];
  const float* b_hh   = (const float*)d_in[4];
  const float* lin1_w = (const float*)d_in[5];
  const float* lin1_b = (const float*)d_in[6];
  const float* lin2_w = (const float*)d_in[7];
  const float* lin2_b = (const float*)d_in[8];
  const float* lin3_w = (const float*)d_in[9];
  const float* lin3_b = (const float*)d_in[10];
  const float* dec_w  = (const float*)d_in[11];
  const float* dec_b  = (const float*)d_in[12];
  const float* embt   = (const float*)d_in[13];

  float* out = (float*)d_out;  // [0..8]=arc, [9..17]=entropy, [18..26]=log_probs
  float* ws = (float*)d_ws;

  float* hA     = ws;              // D   (output of first-cells / final cell)
  float* cA     = ws + D;          // D
  float* hB     = ws + 2 * D;      // D   (output of dec_fused = 2nd cell state)
  float* cB     = ws + 3 * D;      // D
  float* all_c  = ws + 4 * D;      // 4*D
  float* all_cw = ws + 8 * D;      // 4*D
  float* qb     = ws + 12 * D;     // D
  float* logits = ws + 13 * D;     // V = 2*D
  float* g_hh   = ws + 15 * D;     // 4*D  (hh gates + biases)
  float* g_ih   = ws + 19 * D;     // 16*D (4 candidates x 4 gates)
  int* sel_func = (int*)(ws + 35 * D);
  uint16_t* wih_bf = (uint16_t*)(ws + 35 * D + 64);
  uint16_t* whh_bf = wih_bf + (size_t)4 * D * D;
  uint16_t* l1_bf  = whh_bf + (size_t)4 * D * D;
  uint16_t* l2_bf  = l1_bf + (size_t)D * D;

  bool bf = ws_size >= ((size_t)96 << 20);

  if (bf) {
    convert_k<<<20480, 256, 0, stream>>>(w_ih, w_hh, lin1_w, lin2_w,
                                         wih_bf, whh_bf, l1_bf, l2_bf);
  }

  auto launch_spec = [&](int layer) {
    float* cw = all_cw + (size_t)layer * D;
    if (bf) {
      switch (layer) {
        case 0: spec_lin_k<uint16_t, 1><<<1536, 256, 0, stream>>>(wih_bf, whh_bf, b_ih, b_hh, hA, all_c, l1_bf, lin1_b, l2_bf, lin2_b, cA, g_ih, g_hh, cw, qb); break;
        case 1: spec_lin_k<uint16_t, 2><<<1536, 256, 0, stream>>>(wih_bf, whh_bf, b_ih, b_hh, hA, all_c, l1_bf, lin1_b, l2_bf, lin2_b, cA, g_ih, g_hh, cw, qb); break;
        case 2: spec_lin_k<uint16_t, 3><<<1536, 256, 0, stream>>>(wih_bf, whh_bf, b_ih, b_hh, hA, all_c, l1_bf, lin1_b, l2_bf, lin2_b, cA, g_ih, g_hh, cw, qb); break;
        default: spec_lin_k<uint16_t, 4><<<1536, 256, 0, stream>>>(wih_bf, whh_bf, b_ih, b_hh, hA, all_c, l1_bf, lin1_b, l2_bf, lin2_b, cA, g_ih, g_hh, cw, qb); break;
      }
    } else {
      switch (layer) {
        case 0: spec_lin_k<float, 1><<<1536, 256, 0, stream>>>(w_ih, w_hh, b_ih, b_hh, hA, all_c, lin1_w, lin1_b, lin2_w, lin2_b, cA, g_ih, g_hh, cw, qb); break;
        case 1: spec_lin_k<float, 2><<<1536, 256, 0, stream>>>(w_ih, w_hh, b_ih, b_hh, hA, all_c, lin1_w, lin1_b, lin2_w, lin2_b, cA, g_ih, g_hh, cw, qb); break;
        case 2: spec_lin_k<float, 3><<<1536, 256, 0, stream>>>(w_ih, w_hh, b_ih, b_hh, hA, all_c, lin1_w, lin1_b, lin2_w, lin2_b, cA, g_ih, g_hh, cw, qb); break;
        default: spec_lin_k<float, 4><<<1536, 256, 0, stream>>>(w_ih, w_hh, b_ih, b_hh, hA, all_c, lin1_w, lin1_b, lin2_w, lin2_b, cA, g_ih, g_hh, cw, qb); break;
      }
    }
  };

  auto launch_lstm1 = [&](const float* xb, const int* xi, const float* hi, const float* ci,
                          float* ccopy) {
    if (bf) lstm_cell_k<uint16_t><<<D / 4, 256, 0, stream>>>(wih_bf, whh_bf, b_ih, b_hh,
                                                             xb, xi, hi, ci, hA, cA, ccopy);
    else    lstm_cell_k<float><<<D / 4, 256, 0, stream>>>(w_ih, w_hh, b_ih, b_hh,
                                                          xb, xi, hi, ci, hA, cA, ccopy);
  };

  for (int layer = 0; layer < 4; ++layer) {
    // ---- first cell of layer: x = emb0 (L0) or emb_tables[layer-1][func] ----
    if (layer == 0) launch_lstm1(emb0, nullptr, nullptr, nullptr, all_c);
    else launch_lstm1(embt + (size_t)(layer - 1) * V * D, sel_func, hB, cB,
                      all_c + (size_t)layer * D);

    // ---- speculative 2nd-cell gates (all skip candidates) + lin1/lin2 ----
    launch_spec(layer);

    // ---- attn-sample + gate select + c2/h2 + decoder GEMV ----
    int step = 2 * layer;
    dec_fused_k<<<V / 4, 256, 0, stream>>>(dec_w + (size_t)layer * V * D,
                                           dec_b + (size_t)layer * V,
                                           g_ih, g_hh, cA, qb, all_cw, lin3_w, lin3_b,
                                           layer + 1, step, logits, hB, cB,
                                           out + step, out + 9 + step, out + 18 + step);

    // ---- func sample over V=4096 ----
    sample_k<<<1, 1024, 0, stream>>>(logits, step + 1,
                                     out + step + 1, out + 10 + step, out + 19 + step,
                                     sel_func);
  }

  // ---- final cell + decode + sample (step 8) ----
  launch_lstm1(embt + (size_t)3 * V * D, sel_func, hB, cB, nullptr);
  gemv_k<<<V / 4, 256, 0, stream>>>(dec_w + (size_t)4 * V * D, dec_b + (size_t)4 * V,
                                    cA, logits);
  sample_k<<<1, 1024, 0, stream>>>(logits, 8, out + 8, out + 17, out + 26, sel_func);
}

// Round 6
// 282.359 us; speedup vs baseline: 1.2356x; 1.2356x over previous
//
#include <hip/hip_runtime.h>
#include <stdint.h>

#define D 2048
#define V 4096
#define TINYF 1.17549435e-38f
#define NINF (-__builtin_huge_valf())

#if __has_builtin(__builtin_amdgcn_cvt_pk_f32_fp8) && __has_builtin(__builtin_amdgcn_cvt_pk_fp8_f32)
#define HWFP8 1
#define POSTSCALE 0.015625f            /* decode returns w*64 */
#else
#define HWFP8 0
#define POSTSCALE 1.52587890625e-05f   /* decode returns w*64*2^10 */
#endif

typedef float vfloat2 __attribute__((ext_vector_type(2)));
typedef float vfloat4 __attribute__((ext_vector_type(4)));

// ---------------- threefry (JAX partitionable scheme, verified exact R1-R5) --------
__device__ __forceinline__ void tf_block(uint32_t k0, uint32_t k1, uint32_t x0, uint32_t x1,
                                         uint32_t& o0, uint32_t& o1) {
  uint32_t ks2 = k0 ^ k1 ^ 0x1BD11BDAu;
  uint32_t ks[3] = {k0, k1, ks2};
  x0 += k0; x1 += k1;
  const uint32_t rotA[4] = {13u, 15u, 26u, 6u};
  const uint32_t rotB[4] = {17u, 29u, 16u, 24u};
#pragma unroll
  for (int i = 0; i < 5; ++i) {
    const uint32_t* rot = (i & 1) ? rotB : rotA;
#pragma unroll
    for (int j = 0; j < 4; ++j) {
      uint32_t r = rot[j];
      x0 += x1;
      x1 = (x1 << r) | (x1 >> (32u - r));
      x1 ^= x0;
    }
    x0 += ks[(i + 1) % 3];
    x1 += ks[(i + 2) % 3] + (uint32_t)(i + 1);
  }
  o0 = x0; o1 = x1;
}

__device__ __forceinline__ float gumbel_at(uint32_t k1, uint32_t k2, int i) {
  uint32_t o0, o1;
  tf_block(k1, k2, 0u, (uint32_t)i, o0, o1);
  uint32_t bits = o0 ^ o1;
  float u = __uint_as_float((bits >> 9) | 0x3F800000u) - 1.0f;
  u = fmaxf(TINYF, u + TINYF);
  return -logf(-logf(u));
}

// ---------------- fp8 helpers ------------------------------------------------------
#if !HWFP8
__device__ __forceinline__ float dec1(uint32_t v) {
  uint32_t e = (v >> 3) & 15u, m = v & 7u;
  int K = e ? (int)((8u + m) << e) : (int)(m << 1);
  float f = (float)K;
  return (v & 0x80u) ? -f : f;
}
__device__ __forceinline__ uint32_t enc1(float xf) {
  uint32_t b = __float_as_uint(xf);
  uint32_t s = (b >> 24) & 0x80u;
  float ax = fabsf(xf);
  if (ax < 0.015625f) return s | (uint32_t)(int)rintf(ax * 512.f);
  uint32_t ab = b & 0x7FFFFFFFu;
  ab += 0x7FFFFu + ((ab >> 20) & 1u);
  int e = (int)(ab >> 23) - 120;
  uint32_t m = (ab >> 20) & 7u;
  if (e < 1) return s | (uint32_t)(int)rintf(ax * 512.f);
  if (e > 15) { e = 15; m = 7u; }
  return s | ((uint32_t)e << 3) | m;
}
#endif

__device__ __forceinline__ void dec8(uint2 u, float* w) {
#if HWFP8
  vfloat2 a = __builtin_amdgcn_cvt_pk_f32_fp8((int)u.x, false);
  vfloat2 b = __builtin_amdgcn_cvt_pk_f32_fp8((int)u.x, true);
  vfloat2 c = __builtin_amdgcn_cvt_pk_f32_fp8((int)u.y, false);
  vfloat2 d = __builtin_amdgcn_cvt_pk_f32_fp8((int)u.y, true);
  w[0] = a.x; w[1] = a.y; w[2] = b.x; w[3] = b.y;
  w[4] = c.x; w[5] = c.y; w[6] = d.x; w[7] = d.y;
#else
  uint32_t p = u.x, q = u.y;
  w[0] = dec1(p & 255u); w[1] = dec1((p >> 8) & 255u);
  w[2] = dec1((p >> 16) & 255u); w[3] = dec1(p >> 24);
  w[4] = dec1(q & 255u); w[5] = dec1((q >> 8) & 255u);
  w[6] = dec1((q >> 16) & 255u); w[7] = dec1(q >> 24);
#endif
}

// ---------------- misc load helpers ------------------------------------------------
__device__ __forceinline__ float4 ntload4(const float4* p) {
  vfloat4 v = __builtin_nontemporal_load((const vfloat4*)p);
  return make_float4(v.x, v.y, v.z, v.w);
}

// fp8 row · LDS f32 vector (8-weight granularity keeps conflict-free LDS pattern)
__device__ __forceinline__ float row_dot8(const uint8_t* __restrict__ row,
                                          const float* __restrict__ xs, int lane) {
  float a = 0.f;
#pragma unroll
  for (int k = lane * 8; k < D; k += 512) {
    uint2 u = *(const uint2*)(row + k);
    float w[8]; dec8(u, w);
    float4 x0 = *(const float4*)(xs + k);
    float4 x1 = *(const float4*)(xs + k + 4);
    a += w[0] * x0.x + w[1] * x0.y + w[2] * x0.z + w[3] * x0.w
       + w[4] * x1.x + w[5] * x1.y + w[6] * x1.z + w[7] * x1.w;
  }
  return a;
}

// ---------------- f32 -> fp8(x64) weight pack: wih | whh | lin1 | lin2 --------------
__global__ __launch_bounds__(256) void convert_k(const float* __restrict__ wih,
                                                 const float* __restrict__ whh,
                                                 const float* __restrict__ l1,
                                                 const float* __restrict__ l2,
                                                 uint8_t* __restrict__ dw) {
  size_t gid = (size_t)blockIdx.x * 256 + threadIdx.x;  // 8-float chunk id
  const size_t C1 = (size_t)4 * D * D / 8;
  const size_t C2 = 2 * C1;
  const size_t C3 = C2 + (size_t)D * D / 8;
  const size_t C4 = C3 + (size_t)D * D / 8;
  const float* src; size_t off, dbase;
  if (gid < C1)      { src = wih; off = gid;      dbase = 0; }
  else if (gid < C2) { src = whh; off = gid - C1; dbase = (size_t)4 * D * D; }
  else if (gid < C3) { src = l1;  off = gid - C2; dbase = (size_t)8 * D * D; }
  else if (gid < C4) { src = l2;  off = gid - C3; dbase = (size_t)9 * D * D; }
  else return;
  const float4* s = (const float4*)(src + off * 8);
  float4 a = ntload4(s), b = ntload4(s + 1);
  float v[8] = {a.x * 64.f, a.y * 64.f, a.z * 64.f, a.w * 64.f,
                b.x * 64.f, b.y * 64.f, b.z * 64.f, b.w * 64.f};
  uint2 o;
#if HWFP8
  int lo = __builtin_amdgcn_cvt_pk_fp8_f32(v[0], v[1], 0, false);
  lo     = __builtin_amdgcn_cvt_pk_fp8_f32(v[2], v[3], lo, true);
  int hi = __builtin_amdgcn_cvt_pk_fp8_f32(v[4], v[5], 0, false);
  hi     = __builtin_amdgcn_cvt_pk_fp8_f32(v[6], v[7], hi, true);
  o.x = (uint32_t)lo; o.y = (uint32_t)hi;
#else
  o.x = enc1(v[0]) | (enc1(v[1]) << 8) | (enc1(v[2]) << 16) | (enc1(v[3]) << 24);
  o.y = enc1(v[4]) | (enc1(v[5]) << 8) | (enc1(v[6]) << 16) | (enc1(v[7]) << 24);
#endif
  *(uint2*)(dw + dbase + off * 8) = o;
}

// ---------------- LSTM cell; optionally samples func from prev decoder logits -------
template <bool SAMPLE>
__global__ __launch_bounds__(256) void lstm_cell_k(
    const uint8_t* __restrict__ w_ih, const uint8_t* __restrict__ w_hh,
    const float* __restrict__ b_ih, const float* __restrict__ b_hh,
    const float* __restrict__ x_base, const float* __restrict__ logits, int step,
    const float* __restrict__ h_in, const float* __restrict__ c_in,
    float* __restrict__ h_out, float* __restrict__ c_out, float* __restrict__ c_copy,
    float* __restrict__ out_arc, float* __restrict__ out_ent, float* __restrict__ out_lp) {
  __shared__ float xs[D];
  __shared__ float hs[D];
  __shared__ float red[256];
  __shared__ int redi[256];
  __shared__ int s_sel;
  int tid = threadIdx.x;
  const float* x = x_base;
  if (SAMPLE) {
    // redundant per-block V=4096 gumbel argmax (identical result in every block)
    uint32_t k1, k2; tf_block(0u, 42u, 0u, (uint32_t)step, k1, k2);
    float xv[16];
    float m = NINF, bv = NINF; int bi = 1 << 30;
#pragma unroll
    for (int t = 0; t < 16; ++t) {
      int i = tid + t * 256;
      float xl = logits[i];
      xv[t] = xl;
      m = fmaxf(m, xl);
      float sc = gumbel_at(k1, k2, i) + xl;
      if (sc > bv) { bv = sc; bi = i; }   // within-thread i increasing: first-index ties
    }
    red[tid] = m; __syncthreads();
    for (int st = 128; st; st >>= 1) { if (tid < st) red[tid] = fmaxf(red[tid], red[tid + st]); __syncthreads(); }
    m = red[0]; __syncthreads();
    float S = 0.f, T = 0.f;
#pragma unroll
    for (int t = 0; t < 16; ++t) { float e = expf(xv[t] - m); S += e; T += e * (xv[t] - m); }
    red[tid] = S; __syncthreads();
    for (int st = 128; st; st >>= 1) { if (tid < st) red[tid] += red[tid + st]; __syncthreads(); }
    S = red[0]; __syncthreads();
    red[tid] = T; __syncthreads();
    for (int st = 128; st; st >>= 1) { if (tid < st) red[tid] += red[tid + st]; __syncthreads(); }
    T = red[0]; __syncthreads();
    red[tid] = bv; redi[tid] = bi; __syncthreads();
    for (int st = 128; st; st >>= 1) {
      if (tid < st) {
        float ov = red[tid + st]; int oi = redi[tid + st];
        if (ov > red[tid] || (ov == red[tid] && oi < redi[tid])) { red[tid] = ov; redi[tid] = oi; }
      }
      __syncthreads();
    }
    if (tid == 0) {
      int idx = redi[0];
      s_sel = idx;
      if (blockIdx.x == 0) {
        float L = logf(S);
        *out_arc = (float)idx;
        *out_ent = L - T / S;
        *out_lp  = logits[idx] - m - L;
      }
    }
    __syncthreads();
    x = x_base + (size_t)s_sel * D;
  }
  for (int i = tid; i < D; i += 256) { xs[i] = x[i]; hs[i] = h_in ? h_in[i] : 0.f; }
  __syncthreads();
  int wave = tid >> 6, lane = tid & 63;
  int j = blockIdx.x * 4 + wave;
  float gv[4];
#pragma unroll
  for (int m4 = 0; m4 < 4; ++m4) {
    float a = row_dot8(w_ih + (size_t)(m4 * D + j) * D, xs, lane)
            + row_dot8(w_hh + (size_t)(m4 * D + j) * D, hs, lane);
#pragma unroll
    for (int off = 32; off > 0; off >>= 1) a += __shfl_down(a, off, 64);
    gv[m4] = a * POSTSCALE + b_ih[m4 * D + j] + b_hh[m4 * D + j];
  }
  if (lane == 0) {
    float ig = 1.f / (1.f + expf(-gv[0]));
    float fg = 1.f / (1.f + expf(-gv[1]));
    float gg = tanhf(gv[2]);
    float og = 1.f / (1.f + expf(-gv[3]));
    float ci = c_in ? c_in[j] : 0.f;
    float cn = fg * ci + ig * gg;
    float hn = og * tanhf(cn);
    c_out[j] = cn;
    h_out[j] = hn;
    if (c_copy) c_copy[j] = cn;
  }
}

// ---------------- speculative 2nd-cell gates (all candidates) + lin1/lin2 -----------
template <int NC>
__global__ __launch_bounds__(256) void spec_lin_k(
    const uint8_t* __restrict__ w_ih, const uint8_t* __restrict__ w_hh,
    const float* __restrict__ b_ih, const float* __restrict__ b_hh,
    const float* __restrict__ h1, const float* __restrict__ all_c,
    const uint8_t* __restrict__ l1w, const float* __restrict__ l1b,
    const uint8_t* __restrict__ l2w, const float* __restrict__ l2b,
    const float* __restrict__ c1,
    float* __restrict__ g_ih, float* __restrict__ g_hh,
    float* __restrict__ cw_dst, float* __restrict__ qb) {
  __shared__ float xs[D];
  int tid = threadIdx.x;
  int wave = tid >> 6, lane = tid & 63;
  int b = blockIdx.x;
  if (b < 512) {
    int j = b * 4 + wave;
    float acc[4][NC + 1];
#pragma unroll
    for (int m = 0; m < 4; ++m)
#pragma unroll
      for (int t = 0; t < NC + 1; ++t) acc[m][t] = 0.f;
    for (int k = lane * 8; k < D; k += 512) {
      float xh[8];
      float xc[NC][8];
      *(float4*)xh       = *(const float4*)(h1 + k);
      *(float4*)(xh + 4) = *(const float4*)(h1 + k + 4);
#pragma unroll
      for (int t = 0; t < NC; ++t) {
        *(float4*)(xc[t])     = *(const float4*)(all_c + (size_t)t * D + k);
        *(float4*)(xc[t] + 4) = *(const float4*)(all_c + (size_t)t * D + k + 4);
      }
#pragma unroll
      for (int m = 0; m < 4; ++m) {
        float wi[8], wh[8];
        dec8(*(const uint2*)(w_ih + (size_t)(m * D + j) * D + k), wi);
        dec8(*(const uint2*)(w_hh + (size_t)(m * D + j) * D + k), wh);
#pragma unroll
        for (int e = 0; e < 8; ++e) acc[m][0] += wh[e] * xh[e];
#pragma unroll
        for (int t = 0; t < NC; ++t)
#pragma unroll
          for (int e = 0; e < 8; ++e) acc[m][1 + t] += wi[e] * xc[t][e];
      }
    }
#pragma unroll
    for (int m = 0; m < 4; ++m)
#pragma unroll
      for (int t = 0; t < NC + 1; ++t) {
        float a = acc[m][t];
#pragma unroll
        for (int o = 32; o > 0; o >>= 1) a += __shfl_down(a, o, 64);
        if (lane == 0) {
          if (t == 0) g_hh[m * D + j] = a * POSTSCALE + b_ih[m * D + j] + b_hh[m * D + j];
          else        g_ih[((size_t)(t - 1) * 4 + m) * D + j] = a * POSTSCALE;
        }
      }
  } else {
    for (int i = tid; i < D; i += 256) xs[i] = c1[i];
    __syncthreads();
    int b2 = b - 512;
    const uint8_t* Wp; const float* bp; float* dst; int row;
    if (b2 < 512) { row = b2 * 4 + wave; Wp = l1w; bp = l1b; dst = cw_dst; }
    else          { row = (b2 - 512) * 4 + wave; Wp = l2w; bp = l2b; dst = qb; }
    float a = row_dot8(Wp + (size_t)row * D, xs, lane);
#pragma unroll
    for (int o = 32; o > 0; o >>= 1) a += __shfl_down(a, o, 64);
    if (lane == 0) dst[row] = a * POSTSCALE + bp[row];
  }
}

// ---------------- fused: attn-sample + gate select + c2/h2 + decoder GEMV -----------
__global__ __launch_bounds__(256) void dec_fused_k(
    const float* __restrict__ Wdec, const float* __restrict__ bdec,
    const float* __restrict__ g_ih, const float* __restrict__ g_hh,
    const float* __restrict__ c1,
    const float* __restrict__ qb, const float* __restrict__ all_cw,
    const float* __restrict__ lin3_w, const float* __restrict__ lin3_b,
    int ncand, int step,
    float* __restrict__ logits,
    float* __restrict__ h2_out, float* __restrict__ c2_out,
    float* __restrict__ out_arc, float* __restrict__ out_ent, float* __restrict__ out_lp) {
  __shared__ float xs[D];
  __shared__ float red[16];
  __shared__ int s_sel;
  int tid = threadIdx.x, wave = tid >> 6, lane = tid & 63;
  for (int t = 0; t < ncand; ++t) {
    float s = 0.f;
    for (int k = tid; k < D; k += 256) s += tanhf(qb[k] + all_cw[(size_t)t * D + k]) * lin3_w[k];
#pragma unroll
    for (int o = 32; o > 0; o >>= 1) s += __shfl_down(s, o, 64);
    if (lane == 0) red[t * 4 + wave] = s;
  }
  __syncthreads();
  if (tid == 0) {
    float sl[4];
    for (int t = 0; t < ncand; ++t)
      sl[t] = red[t * 4] + red[t * 4 + 1] + red[t * 4 + 2] + red[t * 4 + 3] + lin3_b[0];
    uint32_t k1, k2; tf_block(0u, 42u, 0u, (uint32_t)step, k1, k2);
    float m = NINF;
    for (int i = 0; i < ncand; ++i) m = fmaxf(m, sl[i]);
    float S = 0.f, T = 0.f;
    for (int i = 0; i < ncand; ++i) { float e = expf(sl[i] - m); S += e; T += e * (sl[i] - m); }
    float L = logf(S);
    float bv = NINF; int bi = 0;
    for (int i = 0; i < ncand; ++i) {
      float sc = gumbel_at(k1, k2, i) + sl[i];
      if (sc > bv) { bv = sc; bi = i; }
    }
    s_sel = bi;
    if (blockIdx.x == 0) {
      *out_arc = (float)bi;
      *out_ent = L - T / S;
      *out_lp  = sl[bi] - m - L;
    }
  }
  __syncthreads();
  int sel = s_sel;
  const float* gi = g_ih + (size_t)sel * 4 * D;
  bool b0 = (blockIdx.x == 0);
  for (int j = tid; j < D; j += 256) {
    float gI = gi[j]         + g_hh[j];
    float gF = gi[D + j]     + g_hh[D + j];
    float gG = gi[2 * D + j] + g_hh[2 * D + j];
    float gO = gi[3 * D + j] + g_hh[3 * D + j];
    float ig = 1.f / (1.f + expf(-gI));
    float fg = 1.f / (1.f + expf(-gF));
    float gg = tanhf(gG);
    float og = 1.f / (1.f + expf(-gO));
    float cn = fg * c1[j] + ig * gg;
    xs[j] = cn;
    if (b0) { c2_out[j] = cn; h2_out[j] = og * tanhf(cn); }
  }
  __syncthreads();
  int row = blockIdx.x * 4 + wave;
  const float* wr = Wdec + (size_t)row * D;
  float a = 0.f;
#pragma unroll
  for (int k = lane * 4; k < D; k += 256) {
    float4 w = ntload4((const float4*)(wr + k));
    float4 x = *(const float4*)(xs + k);
    a += w.x * x.x + w.y * x.y + w.z * x.z + w.w * x.w;
  }
#pragma unroll
  for (int o = 32; o > 0; o >>= 1) a += __shfl_down(a, o, 64);
  if (lane == 0) logits[row] = a + bdec[row];
}

// ---------------- final decoder GEMV ------------------------------------------------
__global__ __launch_bounds__(256) void gemv_k(const float* __restrict__ W,
                                              const float* __restrict__ bias,
                                              const float* __restrict__ c,
                                              float* __restrict__ y) {
  __shared__ float xs[D];
  int tid = threadIdx.x;
  for (int i = tid; i < D; i += 256) xs[i] = c[i];
  __syncthreads();
  int wave = tid >> 6, lane = tid & 63;
  int row = blockIdx.x * 4 + wave;
  const float* wr = W + (size_t)row * D;
  float a = 0.f;
#pragma unroll
  for (int k = lane * 4; k < D; k += 256) {
    float4 w = ntload4((const float4*)(wr + k));
    float4 x = *(const float4*)(xs + k);
    a += w.x * x.x + w.y * x.y + w.z * x.z + w.w * x.w;
  }
#pragma unroll
  for (int o = 32; o > 0; o >>= 1) a += __shfl_down(a, o, 64);
  if (lane == 0) y[row] = a + bias[row];
}

// ---------------- V=4096 sampler (final step only) ----------------------------------
__global__ __launch_bounds__(1024) void sample_k(const float* __restrict__ logits, int step,
                                                 float* __restrict__ out_arc,
                                                 float* __restrict__ out_ent,
                                                 float* __restrict__ out_lp,
                                                 int* __restrict__ sel_out) {
  __shared__ float red[1024];
  __shared__ int redi[1024];
  int tid = threadIdx.x;
  uint32_t k1, k2; tf_block(0u, 42u, 0u, (uint32_t)step, k1, k2);
  float xv[4];
  float m = NINF, bv = NINF; int bi = 1 << 30;
#pragma unroll
  for (int t = 0; t < 4; ++t) {
    int i = tid + t * 1024;
    float x = logits[i];
    xv[t] = x;
    m = fmaxf(m, x);
    float sc = gumbel_at(k1, k2, i) + x;
    if (sc > bv) { bv = sc; bi = i; }
  }
  red[tid] = m; __syncthreads();
  for (int st = 512; st; st >>= 1) { if (tid < st) red[tid] = fmaxf(red[tid], red[tid + st]); __syncthreads(); }
  m = red[0]; __syncthreads();
  float S = 0.f, T = 0.f;
#pragma unroll
  for (int t = 0; t < 4; ++t) { float e = expf(xv[t] - m); S += e; T += e * (xv[t] - m); }
  red[tid] = S; __syncthreads();
  for (int st = 512; st; st >>= 1) { if (tid < st) red[tid] += red[tid + st]; __syncthreads(); }
  S = red[0]; __syncthreads();
  red[tid] = T; __syncthreads();
  for (int st = 512; st; st >>= 1) { if (tid < st) red[tid] += red[tid + st]; __syncthreads(); }
  T = red[0]; __syncthreads();
  red[tid] = bv; redi[tid] = bi; __syncthreads();
  for (int st = 512; st; st >>= 1) {
    if (tid < st) {
      float ov = red[tid + st]; int oi = redi[tid + st];
      if (ov > red[tid] || (ov == red[tid] && oi < redi[tid])) { red[tid] = ov; redi[tid] = oi; }
    }
    __syncthreads();
  }
  if (tid == 0) {
    float L = logf(S);
    int idx = redi[0];
    *out_arc = (float)idx;
    *out_ent = L - T / S;
    *out_lp  = logits[idx] - m - L;
    *sel_out = idx;
  }
}

// ---------------- host-side orchestration ------------------------------------------
extern "C" void kernel_launch(void* const* d_in, const int* in_sizes, int n_in,
                              void* d_out, int out_size, void* d_ws, size_t ws_size,
                              hipStream_t stream) {
  const float* emb0   = (const float*)d_in[0];
  const float* w_ih   = (const float*)d_in[1];
  const float* w_hh   = (const float*)d_in[2];
  const float* b_ih   = (const float*)d_in[3];
  const float* b_hh   = (const float*)d_in[4];
  const float* lin1_w = (const float*)d_in[5];
  const float* lin1_b = (const float*)d_in[6];
  const float* lin2_w = (const float*)d_in[7];
  const float* lin2_b = (const float*)d_in[8];
  const float* lin3_w = (const float*)d_in[9];
  const float* lin3_b = (const float*)d_in[10];
  const float* dec_w  = (const float*)d_in[11];
  const float* dec_b  = (const float*)d_in[12];
  const float* embt   = (const float*)d_in[13];

  float* out = (float*)d_out;  // [0..8]=arc, [9..17]=entropy, [18..26]=log_probs
  float* ws = (float*)d_ws;

  float* hA     = ws;              // D   (first-cell / final-cell h)
  float* cA     = ws + D;          // D
  float* hB     = ws + 2 * D;      // D   (2nd-cell h, written by dec_fused)
  float* cB     = ws + 3 * D;      // D
  float* all_c  = ws + 4 * D;      // 4*D
  float* all_cw = ws + 8 * D;      // 4*D
  float* qb     = ws + 12 * D;     // D
  float* logits = ws + 13 * D;     // V = 2*D
  int* sel_d    = (int*)(ws + 15 * D);
  float* g_hh   = ws + 16 * D;     // 4*D
  float* g_ih   = ws + 20 * D;     // 16*D
  uint8_t* w8   = (uint8_t*)(ws + 36 * D);   // fp8: wih(4DD) whh(4DD) l1(DD) l2(DD)
  uint8_t* wih8 = w8;
  uint8_t* whh8 = w8 + (size_t)4 * D * D;
  uint8_t* l18  = w8 + (size_t)8 * D * D;
  uint8_t* l28  = w8 + (size_t)9 * D * D;

  convert_k<<<20480, 256, 0, stream>>>(w_ih, w_hh, lin1_w, lin2_w, w8);

  auto launch_spec = [&](int layer) {
    float* cw = all_cw + (size_t)layer * D;
    switch (layer) {
      case 0:  spec_lin_k<1><<<1536, 256, 0, stream>>>(wih8, whh8, b_ih, b_hh, hA, all_c, l18, lin1_b, l28, lin2_b, cA, g_ih, g_hh, cw, qb); break;
      case 1:  spec_lin_k<2><<<1536, 256, 0, stream>>>(wih8, whh8, b_ih, b_hh, hA, all_c, l18, lin1_b, l28, lin2_b, cA, g_ih, g_hh, cw, qb); break;
      case 2:  spec_lin_k<3><<<1536, 256, 0, stream>>>(wih8, whh8, b_ih, b_hh, hA, all_c, l18, lin1_b, l28, lin2_b, cA, g_ih, g_hh, cw, qb); break;
      default: spec_lin_k<4><<<1536, 256, 0, stream>>>(wih8, whh8, b_ih, b_hh, hA, all_c, l18, lin1_b, l28, lin2_b, cA, g_ih, g_hh, cw, qb); break;
    }
  };

  for (int layer = 0; layer < 4; ++layer) {
    float* ccopy = all_c + (size_t)layer * D;
    if (layer == 0) {
      lstm_cell_k<false><<<512, 256, 0, stream>>>(wih8, whh8, b_ih, b_hh,
                                                  emb0, nullptr, 0,
                                                  nullptr, nullptr, hA, cA, ccopy,
                                                  nullptr, nullptr, nullptr);
    } else {
      int ps = 2 * layer - 1;  // func-sample step of previous layer
      lstm_cell_k<true><<<512, 256, 0, stream>>>(wih8, whh8, b_ih, b_hh,
                                                 embt + (size_t)(layer - 1) * V * D,
                                                 logits, ps,
                                                 hB, cB, hA, cA, ccopy,
                                                 out + ps, out + 9 + ps, out + 18 + ps);
    }
    launch_spec(layer);
    int step = 2 * layer;
    dec_fused_k<<<V / 4, 256, 0, stream>>>(dec_w + (size_t)layer * V * D,
                                           dec_b + (size_t)layer * V,
                                           g_ih, g_hh, cA, qb, all_cw, lin3_w, lin3_b,
                                           layer + 1, step, logits, hB, cB,
                                           out + step, out + 9 + step, out + 18 + step);
  }

  // final cell (samples step 7) + decode + sample (step 8)
  lstm_cell_k<true><<<512, 256, 0, stream>>>(wih8, whh8, b_ih, b_hh,
                                             embt + (size_t)3 * V * D, logits, 7,
                                             hB, cB, hA, cA, nullptr,
                                             out + 7, out + 16, out + 25);
  gemv_k<<<V / 4, 256, 0, stream>>>(dec_w + (size_t)4 * V * D, dec_b + (size_t)4 * V,
                                    cA, logits);
  sample_k<<<1, 1024, 0, stream>>>(logits, 8, out + 8, out + 17, out + 26, sel_d);
}

// Round 7
// 265.797 us; speedup vs baseline: 1.3126x; 1.0623x over previous
//
#include <hip/hip_runtime.h>
#include <stdint.h>

#define D 2048
#define V 4096
#define TINYF 1.17549435e-38f
#define NINF (-__builtin_huge_valf())

#if __has_builtin(__builtin_amdgcn_cvt_pk_f32_fp8) && __has_builtin(__builtin_amdgcn_cvt_pk_fp8_f32)
#define HWFP8 1
#define POSTSCALE 0.015625f            /* decode returns w*64 */
#else
#define HWFP8 0
#define POSTSCALE 1.52587890625e-05f   /* decode returns w*64*2^10 */
#endif

typedef float vfloat2 __attribute__((ext_vector_type(2)));
typedef float vfloat4 __attribute__((ext_vector_type(4)));

// ---------------- threefry (JAX partitionable scheme, verified exact R1-R6) --------
__device__ __forceinline__ void tf_block(uint32_t k0, uint32_t k1, uint32_t x0, uint32_t x1,
                                         uint32_t& o0, uint32_t& o1) {
  uint32_t ks2 = k0 ^ k1 ^ 0x1BD11BDAu;
  uint32_t ks[3] = {k0, k1, ks2};
  x0 += k0; x1 += k1;
  const uint32_t rotA[4] = {13u, 15u, 26u, 6u};
  const uint32_t rotB[4] = {17u, 29u, 16u, 24u};
#pragma unroll
  for (int i = 0; i < 5; ++i) {
    const uint32_t* rot = (i & 1) ? rotB : rotA;
#pragma unroll
    for (int j = 0; j < 4; ++j) {
      uint32_t r = rot[j];
      x0 += x1;
      x1 = (x1 << r) | (x1 >> (32u - r));
      x1 ^= x0;
    }
    x0 += ks[(i + 1) % 3];
    x1 += ks[(i + 2) % 3] + (uint32_t)(i + 1);
  }
  o0 = x0; o1 = x1;
}

__device__ __forceinline__ float gumbel_at(uint32_t k1, uint32_t k2, int i) {
  uint32_t o0, o1;
  tf_block(k1, k2, 0u, (uint32_t)i, o0, o1);
  uint32_t bits = o0 ^ o1;
  float u = __uint_as_float((bits >> 9) | 0x3F800000u) - 1.0f;
  u = fmaxf(TINYF, u + TINYF);
  return -logf(-logf(u));
}

// ---------------- fp8 helpers ------------------------------------------------------
#if !HWFP8
__device__ __forceinline__ float dec1(uint32_t v) {
  uint32_t e = (v >> 3) & 15u, m = v & 7u;
  int K = e ? (int)((8u + m) << e) : (int)(m << 1);
  float f = (float)K;
  return (v & 0x80u) ? -f : f;
}
__device__ __forceinline__ uint32_t enc1(float xf) {
  uint32_t b = __float_as_uint(xf);
  uint32_t s = (b >> 24) & 0x80u;
  float ax = fabsf(xf);
  if (ax < 0.015625f) return s | (uint32_t)(int)rintf(ax * 512.f);
  uint32_t ab = b & 0x7FFFFFFFu;
  ab += 0x7FFFFu + ((ab >> 20) & 1u);
  int e = (int)(ab >> 23) - 120;
  uint32_t m = (ab >> 20) & 7u;
  if (e < 1) return s | (uint32_t)(int)rintf(ax * 512.f);
  if (e > 15) { e = 15; m = 7u; }
  return s | ((uint32_t)e << 3) | m;
}
#endif

__device__ __forceinline__ void dec8(uint2 u, float* w) {
#if HWFP8
  vfloat2 a = __builtin_amdgcn_cvt_pk_f32_fp8((int)u.x, false);
  vfloat2 b = __builtin_amdgcn_cvt_pk_f32_fp8((int)u.x, true);
  vfloat2 c = __builtin_amdgcn_cvt_pk_f32_fp8((int)u.y, false);
  vfloat2 d = __builtin_amdgcn_cvt_pk_f32_fp8((int)u.y, true);
  w[0] = a.x; w[1] = a.y; w[2] = b.x; w[3] = b.y;
  w[4] = c.x; w[5] = c.y; w[6] = d.x; w[7] = d.y;
#else
  uint32_t p = u.x, q = u.y;
  w[0] = dec1(p & 255u); w[1] = dec1((p >> 8) & 255u);
  w[2] = dec1((p >> 16) & 255u); w[3] = dec1(p >> 24);
  w[4] = dec1(q & 255u); w[5] = dec1((q >> 8) & 255u);
  w[6] = dec1((q >> 16) & 255u); w[7] = dec1(q >> 24);
#endif
}

__device__ __forceinline__ uint2 enc8(const float* v) {  // v[e] = w*64
  uint2 o;
#if HWFP8
  int lo = __builtin_amdgcn_cvt_pk_fp8_f32(v[0], v[1], 0, false);
  lo     = __builtin_amdgcn_cvt_pk_fp8_f32(v[2], v[3], lo, true);
  int hi = __builtin_amdgcn_cvt_pk_fp8_f32(v[4], v[5], 0, false);
  hi     = __builtin_amdgcn_cvt_pk_fp8_f32(v[6], v[7], hi, true);
  o.x = (uint32_t)lo; o.y = (uint32_t)hi;
#else
  o.x = enc1(v[0]) | (enc1(v[1]) << 8) | (enc1(v[2]) << 16) | (enc1(v[3]) << 24);
  o.y = enc1(v[4]) | (enc1(v[5]) << 8) | (enc1(v[6]) << 16) | (enc1(v[7]) << 24);
#endif
  return o;
}

// ---------------- misc load helpers ------------------------------------------------
__device__ __forceinline__ float4 ntload4(const float4* p) {
  vfloat4 v = __builtin_nontemporal_load((const vfloat4*)p);
  return make_float4(v.x, v.y, v.z, v.w);
}

// fp8 row · LDS f32 vector
__device__ __forceinline__ float row_dot8(const uint8_t* __restrict__ row,
                                          const float* __restrict__ xs, int lane) {
  float a = 0.f;
#pragma unroll
  for (int k = lane * 8; k < D; k += 512) {
    uint2 u = *(const uint2*)(row + k);
    float w[8]; dec8(u, w);
    float4 x0 = *(const float4*)(xs + k);
    float4 x1 = *(const float4*)(xs + k + 4);
    a += w[0] * x0.x + w[1] * x0.y + w[2] * x0.z + w[3] * x0.w
       + w[4] * x1.x + w[5] * x1.y + w[6] * x1.z + w[7] * x1.w;
  }
  return a;
}

// f32 row · LDS vector, NT load, side-writes fp8(x64) copy
__device__ __forceinline__ float row_dot_conv(const float* __restrict__ row,
                                              const float* __restrict__ xs, int lane,
                                              uint8_t* __restrict__ out8) {
  float a = 0.f;
#pragma unroll
  for (int k = lane * 8; k < D; k += 512) {
    float4 w0 = ntload4((const float4*)(row + k));
    float4 w1 = ntload4((const float4*)(row + k + 4));
    float4 x0 = *(const float4*)(xs + k);
    float4 x1 = *(const float4*)(xs + k + 4);
    a += w0.x * x0.x + w0.y * x0.y + w0.z * x0.z + w0.w * x0.w
       + w1.x * x1.x + w1.y * x1.y + w1.z * x1.z + w1.w * x1.w;
    float v[8] = {w0.x * 64.f, w0.y * 64.f, w0.z * 64.f, w0.w * 64.f,
                  w1.x * 64.f, w1.y * 64.f, w1.z * 64.f, w1.w * 64.f};
    *(uint2*)(out8 + k) = enc8(v);
  }
  return a;
}

// ---------------- partial-sample merge (max / S / T / gumbel-argmax) ----------------
struct SampPart { float m, S, T, bv; int bi; };

__device__ __forceinline__ void merge_part(SampPart& a, float qm, float qS, float qT,
                                           float qb, int qi) {
  float nm = fmaxf(a.m, qm);
  float ea = expf(a.m - nm), eq = expf(qm - nm);
  a.T = (a.T + (a.m - nm) * a.S) * ea + (qT + (qm - nm) * qS) * eq;
  a.S = a.S * ea + qS * eq;
  a.m = nm;
  if (qb > a.bv || (qb == a.bv && qi < a.bi)) { a.bv = qb; a.bi = qi; }
}

// reduce 1024 partials across 256 threads; returns final in thread 0's copy via LDS
__device__ __forceinline__ SampPart reduce_parts(const float4* __restrict__ part4,
                                                 const int* __restrict__ parti,
                                                 float* rm, float* rS, float* rT,
                                                 float* rb, int* ri, int tid) {
  float4 p = part4[4 * tid];
  SampPart a = {p.x, p.y, p.z, p.w, parti[4 * tid]};
#pragma unroll
  for (int r = 1; r < 4; ++r) {
    float4 q = part4[4 * tid + r];
    merge_part(a, q.x, q.y, q.z, q.w, parti[4 * tid + r]);
  }
  rm[tid] = a.m; rS[tid] = a.S; rT[tid] = a.T; rb[tid] = a.bv; ri[tid] = a.bi;
  __syncthreads();
  for (int st = 128; st; st >>= 1) {
    if (tid < st) {
      merge_part(a, rm[tid + st], rS[tid + st], rT[tid + st], rb[tid + st], ri[tid + st]);
      rm[tid] = a.m; rS[tid] = a.S; rT[tid] = a.T; rb[tid] = a.bv; ri[tid] = a.bi;
    }
    __syncthreads();
  }
  SampPart res = {rm[0], rS[0], rT[0], rb[0], ri[0]};
  __syncthreads();
  return res;
}

// per-block partial over 4 logit rows (base..base+3) for func-sample at key `step`
__device__ __forceinline__ void block_partial(const float* sl4, int base, int step,
                                              float4* __restrict__ part4,
                                              int* __restrict__ parti, int blk) {
  uint32_t k1, k2; tf_block(0u, 42u, 0u, (uint32_t)step, k1, k2);
  float x0 = sl4[0], x1 = sl4[1], x2 = sl4[2], x3 = sl4[3];
  float pm = fmaxf(fmaxf(x0, x1), fmaxf(x2, x3));
  float e0 = expf(x0 - pm), e1 = expf(x1 - pm), e2 = expf(x2 - pm), e3 = expf(x3 - pm);
  float pS = e0 + e1 + e2 + e3;
  float pT = e0 * (x0 - pm) + e1 * (x1 - pm) + e2 * (x2 - pm) + e3 * (x3 - pm);
  float pb = NINF; int pbi = base;
  float g;
  g = gumbel_at(k1, k2, base + 0) + x0; if (g > pb) { pb = g; pbi = base + 0; }
  g = gumbel_at(k1, k2, base + 1) + x1; if (g > pb) { pb = g; pbi = base + 1; }
  g = gumbel_at(k1, k2, base + 2) + x2; if (g > pb) { pb = g; pbi = base + 2; }
  g = gumbel_at(k1, k2, base + 3) + x3; if (g > pb) { pb = g; pbi = base + 3; }
  part4[blk] = make_float4(pm, pS, pT, pb);
  parti[blk] = pbi;
}

// ---------------- LSTM cell --------------------------------------------------------
// CONV: read f32 weights (layer 0), side-write fp8 copies. SAMPLE: consume 1024
// func-sample partials from the preceding decoder kernel, pick x = x_base[sel].
template <bool CONV, bool SAMPLE>
__global__ __launch_bounds__(256) void lstm_cell_k(
    const void* __restrict__ w_ih_v, const void* __restrict__ w_hh_v,
    uint8_t* __restrict__ wih8_out, uint8_t* __restrict__ whh8_out,
    const float* __restrict__ b_ih, const float* __restrict__ b_hh,
    const float* __restrict__ x_base,
    const float4* __restrict__ part4, const int* __restrict__ parti,
    const float* __restrict__ logits,
    const float* __restrict__ h_in, const float* __restrict__ c_in,
    float* __restrict__ h_out, float* __restrict__ c_out, float* __restrict__ c_copy,
    float* __restrict__ out_arc, float* __restrict__ out_ent, float* __restrict__ out_lp) {
  __shared__ float xs[D];
  __shared__ float hs[D];
  __shared__ float rm[256], rS[256], rT[256], rb[256];
  __shared__ int ri[256];
  int tid = threadIdx.x;
  const float* x = x_base;
  if (SAMPLE) {
    SampPart g = reduce_parts(part4, parti, rm, rS, rT, rb, ri, tid);
    if (tid == 0 && blockIdx.x == 0) {
      float L = logf(g.S);
      *out_arc = (float)g.bi;
      *out_ent = L - g.T / g.S;
      *out_lp  = logits[g.bi] - g.m - L;
    }
    x = x_base + (size_t)g.bi * D;
  }
  for (int i = tid; i < D; i += 256) { xs[i] = x[i]; hs[i] = h_in ? h_in[i] : 0.f; }
  __syncthreads();
  int wave = tid >> 6, lane = tid & 63;
  int j = blockIdx.x * 4 + wave;
  float gv[4];
#pragma unroll
  for (int m4 = 0; m4 < 4; ++m4) {
    size_t roff = (size_t)(m4 * D + j) * D;
    float a;
    if (CONV) {
      a = row_dot_conv((const float*)w_ih_v + roff, xs, lane, wih8_out + roff)
        + row_dot_conv((const float*)w_hh_v + roff, hs, lane, whh8_out + roff);
    } else {
      a = row_dot8((const uint8_t*)w_ih_v + roff, xs, lane)
        + row_dot8((const uint8_t*)w_hh_v + roff, hs, lane);
      a *= POSTSCALE;
    }
#pragma unroll
    for (int off = 32; off > 0; off >>= 1) a += __shfl_down(a, off, 64);
    gv[m4] = a + b_ih[m4 * D + j] + b_hh[m4 * D + j];
  }
  if (lane == 0) {
    float ig = 1.f / (1.f + expf(-gv[0]));
    float fg = 1.f / (1.f + expf(-gv[1]));
    float gg = tanhf(gv[2]);
    float og = 1.f / (1.f + expf(-gv[3]));
    float ci = c_in ? c_in[j] : 0.f;
    float cn = fg * ci + ig * gg;
    float hn = og * tanhf(cn);
    c_out[j] = cn;
    h_out[j] = hn;
    if (c_copy) c_copy[j] = cn;
  }
}

// ---------------- speculative 2nd-cell gates + lin1/lin2 ----------------------------
// gate blocks [0,512): fp8 wih/whh (written by layer-0 lstm when CONV).
// lin blocks [512,1536): layer 0 (CONV) reads f32 lin1/lin2 + writes fp8; else fp8.
template <int NC, bool CONV>
__global__ __launch_bounds__(256) void spec_lin_k(
    const uint8_t* __restrict__ w_ih, const uint8_t* __restrict__ w_hh,
    const float* __restrict__ b_ih, const float* __restrict__ b_hh,
    const float* __restrict__ h1, const float* __restrict__ all_c,
    const void* __restrict__ l1_v, const float* __restrict__ l1b,
    const void* __restrict__ l2_v, const float* __restrict__ l2b,
    uint8_t* __restrict__ l18_out, uint8_t* __restrict__ l28_out,
    const float* __restrict__ c1,
    float* __restrict__ g_ih, float* __restrict__ g_hh,
    float* __restrict__ cw_dst, float* __restrict__ qb) {
  __shared__ float xs[D];
  int tid = threadIdx.x;
  int wave = tid >> 6, lane = tid & 63;
  int b = blockIdx.x;
  if (b < 512) {
    int j = b * 4 + wave;
    float acc[4][NC + 1];
#pragma unroll
    for (int m = 0; m < 4; ++m)
#pragma unroll
      for (int t = 0; t < NC + 1; ++t) acc[m][t] = 0.f;
    for (int k = lane * 8; k < D; k += 512) {
      float xh[8];
      float xc[NC][8];
      *(float4*)xh       = *(const float4*)(h1 + k);
      *(float4*)(xh + 4) = *(const float4*)(h1 + k + 4);
#pragma unroll
      for (int t = 0; t < NC; ++t) {
        *(float4*)(xc[t])     = *(const float4*)(all_c + (size_t)t * D + k);
        *(float4*)(xc[t] + 4) = *(const float4*)(all_c + (size_t)t * D + k + 4);
      }
#pragma unroll
      for (int m = 0; m < 4; ++m) {
        float wi[8], wh[8];
        dec8(*(const uint2*)(w_ih + (size_t)(m * D + j) * D + k), wi);
        dec8(*(const uint2*)(w_hh + (size_t)(m * D + j) * D + k), wh);
#pragma unroll
        for (int e = 0; e < 8; ++e) acc[m][0] += wh[e] * xh[e];
#pragma unroll
        for (int t = 0; t < NC; ++t)
#pragma unroll
          for (int e = 0; e < 8; ++e) acc[m][1 + t] += wi[e] * xc[t][e];
      }
    }
#pragma unroll
    for (int m = 0; m < 4; ++m)
#pragma unroll
      for (int t = 0; t < NC + 1; ++t) {
        float a = acc[m][t];
#pragma unroll
        for (int o = 32; o > 0; o >>= 1) a += __shfl_down(a, o, 64);
        if (lane == 0) {
          if (t == 0) g_hh[m * D + j] = a * POSTSCALE + b_ih[m * D + j] + b_hh[m * D + j];
          else        g_ih[((size_t)(t - 1) * 4 + m) * D + j] = a * POSTSCALE;
        }
      }
  } else {
    for (int i = tid; i < D; i += 256) xs[i] = c1[i];
    __syncthreads();
    int b2 = b - 512;
    const void* Wp; const float* bp; float* dst; uint8_t* o8; int row;
    if (b2 < 512) { row = b2 * 4 + wave; Wp = l1_v; bp = l1b; dst = cw_dst; o8 = l18_out; }
    else          { row = (b2 - 512) * 4 + wave; Wp = l2_v; bp = l2b; dst = qb; o8 = l28_out; }
    size_t roff = (size_t)row * D;
    float a;
    if (CONV) a = row_dot_conv((const float*)Wp + roff, xs, lane, o8 + roff);
    else      a = row_dot8((const uint8_t*)Wp + roff, xs, lane) * POSTSCALE;
#pragma unroll
    for (int o = 32; o > 0; o >>= 1) a += __shfl_down(a, o, 64);
    if (lane == 0) dst[row] = a + bp[row];
  }
}

// ---------------- fused: attn-sample + gate select + c2/h2 + decoder GEMV
//                  + per-block func-sample partial (key step+1) -----------------------
__global__ __launch_bounds__(256) void dec_fused_k(
    const float* __restrict__ Wdec, const float* __restrict__ bdec,
    const float* __restrict__ g_ih, const float* __restrict__ g_hh,
    const float* __restrict__ c1,
    const float* __restrict__ qb, const float* __restrict__ all_cw,
    const float* __restrict__ lin3_w, const float* __restrict__ lin3_b,
    int ncand, int step,
    float* __restrict__ logits,
    float* __restrict__ h2_out, float* __restrict__ c2_out,
    float* __restrict__ out_arc, float* __restrict__ out_ent, float* __restrict__ out_lp,
    float4* __restrict__ part4, int* __restrict__ parti) {
  __shared__ float xs[D];
  __shared__ float red[16];
  __shared__ float sl4[4];
  __shared__ int s_sel;
  int tid = threadIdx.x, wave = tid >> 6, lane = tid & 63;
  for (int t = 0; t < ncand; ++t) {
    float s = 0.f;
    for (int k = tid; k < D; k += 256) s += tanhf(qb[k] + all_cw[(size_t)t * D + k]) * lin3_w[k];
#pragma unroll
    for (int o = 32; o > 0; o >>= 1) s += __shfl_down(s, o, 64);
    if (lane == 0) red[t * 4 + wave] = s;
  }
  __syncthreads();
  if (tid == 0) {
    float sl[4];
    for (int t = 0; t < ncand; ++t)
      sl[t] = red[t * 4] + red[t * 4 + 1] + red[t * 4 + 2] + red[t * 4 + 3] + lin3_b[0];
    uint32_t k1, k2; tf_block(0u, 42u, 0u, (uint32_t)step, k1, k2);
    float m = NINF;
    for (int i = 0; i < ncand; ++i) m = fmaxf(m, sl[i]);
    float S = 0.f, T = 0.f;
    for (int i = 0; i < ncand; ++i) { float e = expf(sl[i] - m); S += e; T += e * (sl[i] - m); }
    float L = logf(S);
    float bv = NINF; int bi = 0;
    for (int i = 0; i < ncand; ++i) {
      float sc = gumbel_at(k1, k2, i) + sl[i];
      if (sc > bv) { bv = sc; bi = i; }
    }
    s_sel = bi;
    if (blockIdx.x == 0) {
      *out_arc = (float)bi;
      *out_ent = L - T / S;
      *out_lp  = sl[bi] - m - L;
    }
  }
  __syncthreads();
  int sel = s_sel;
  const float* gi = g_ih + (size_t)sel * 4 * D;
  bool b0 = (blockIdx.x == 0);
  for (int j = tid; j < D; j += 256) {
    float gI = gi[j]         + g_hh[j];
    float gF = gi[D + j]     + g_hh[D + j];
    float gG = gi[2 * D + j] + g_hh[2 * D + j];
    float gO = gi[3 * D + j] + g_hh[3 * D + j];
    float ig = 1.f / (1.f + expf(-gI));
    float fg = 1.f / (1.f + expf(-gF));
    float gg = tanhf(gG);
    float og = 1.f / (1.f + expf(-gO));
    float cn = fg * c1[j] + ig * gg;
    xs[j] = cn;
    if (b0) { c2_out[j] = cn; h2_out[j] = og * tanhf(cn); }
  }
  __syncthreads();
  int row = blockIdx.x * 4 + wave;
  const float* wr = Wdec + (size_t)row * D;
  float a = 0.f;
#pragma unroll
  for (int k = lane * 4; k < D; k += 256) {
    float4 w = ntload4((const float4*)(wr + k));
    float4 x = *(const float4*)(xs + k);
    a += w.x * x.x + w.y * x.y + w.z * x.z + w.w * x.w;
  }
#pragma unroll
  for (int o = 32; o > 0; o >>= 1) a += __shfl_down(a, o, 64);
  if (lane == 0) { float lv = a + bdec[row]; logits[row] = lv; sl4[wave] = lv; }
  __syncthreads();
  if (tid == 0) block_partial(sl4, blockIdx.x * 4, step + 1, part4, parti, blockIdx.x);
}

// ---------------- final decoder GEMV + partial tail (key step) -----------------------
__global__ __launch_bounds__(256) void gemv_k(
    const float* __restrict__ W, const float* __restrict__ bias,
    const float* __restrict__ c, float* __restrict__ y, int step,
    float4* __restrict__ part4, int* __restrict__ parti) {
  __shared__ float xs[D];
  __shared__ float sl4[4];
  int tid = threadIdx.x;
  for (int i = tid; i < D; i += 256) xs[i] = c[i];
  __syncthreads();
  int wave = tid >> 6, lane = tid & 63;
  int row = blockIdx.x * 4 + wave;
  const float* wr = W + (size_t)row * D;
  float a = 0.f;
#pragma unroll
  for (int k = lane * 4; k < D; k += 256) {
    float4 w = ntload4((const float4*)(wr + k));
    float4 x = *(const float4*)(xs + k);
    a += w.x * x.x + w.y * x.y + w.z * x.z + w.w * x.w;
  }
#pragma unroll
  for (int o = 32; o > 0; o >>= 1) a += __shfl_down(a, o, 64);
  if (lane == 0) { float lv = a + bias[row]; y[row] = lv; sl4[wave] = lv; }
  __syncthreads();
  if (tid == 0) block_partial(sl4, blockIdx.x * 4, step, part4, parti, blockIdx.x);
}

// ---------------- final partial reduce -> outputs (step 8) ---------------------------
__global__ __launch_bounds__(256) void reduce_sample_k(
    const float4* __restrict__ part4, const int* __restrict__ parti,
    const float* __restrict__ logits,
    float* __restrict__ out_arc, float* __restrict__ out_ent, float* __restrict__ out_lp) {
  __shared__ float rm[256], rS[256], rT[256], rb[256];
  __shared__ int ri[256];
  int tid = threadIdx.x;
  SampPart g = reduce_parts(part4, parti, rm, rS, rT, rb, ri, tid);
  if (tid == 0) {
    float L = logf(g.S);
    *out_arc = (float)g.bi;
    *out_ent = L - g.T / g.S;
    *out_lp  = logits[g.bi] - g.m - L;
  }
}

// ---------------- host-side orchestration ------------------------------------------
extern "C" void kernel_launch(void* const* d_in, const int* in_sizes, int n_in,
                              void* d_out, int out_size, void* d_ws, size_t ws_size,
                              hipStream_t stream) {
  const float* emb0   = (const float*)d_in[0];
  const float* w_ih   = (const float*)d_in[1];
  const float* w_hh   = (const float*)d_in[2];
  const float* b_ih   = (const float*)d_in[3];
  const float* b_hh   = (const float*)d_in[4];
  const float* lin1_w = (const float*)d_in[5];
  const float* lin1_b = (const float*)d_in[6];
  const float* lin2_w = (const float*)d_in[7];
  const float* lin2_b = (const float*)d_in[8];
  const float* lin3_w = (const float*)d_in[9];
  const float* lin3_b = (const float*)d_in[10];
  const float* dec_w  = (const float*)d_in[11];
  const float* dec_b  = (const float*)d_in[12];
  const float* embt   = (const float*)d_in[13];

  float* out = (float*)d_out;  // [0..8]=arc, [9..17]=entropy, [18..26]=log_probs
  float* ws = (float*)d_ws;

  float* hA     = ws;              // D   (first-cell / final-cell h)
  float* cA     = ws + D;          // D
  float* hB     = ws + 2 * D;      // D   (2nd-cell h, written by dec_fused)
  float* cB     = ws + 3 * D;      // D
  float* all_c  = ws + 4 * D;      // 4*D
  float* all_cw = ws + 8 * D;      // 4*D
  float* qb     = ws + 12 * D;     // D
  float* logits = ws + 13 * D;     // V = 2*D
  float* g_hh   = ws + 15 * D;     // 4*D
  float* g_ih   = ws + 19 * D;     // 16*D
  float4* part4 = (float4*)(ws + 36 * D);       // 1024 float4 = 2*D floats
  int* parti    = (int*)(ws + 38 * D);          // 1024 ints
  uint8_t* w8   = (uint8_t*)(ws + 40 * D);      // fp8: wih(4DD) whh(4DD) l1(DD) l2(DD)
  uint8_t* wih8 = w8;
  uint8_t* whh8 = w8 + (size_t)4 * D * D;
  uint8_t* l18  = w8 + (size_t)8 * D * D;
  uint8_t* l28  = w8 + (size_t)9 * D * D;

  for (int layer = 0; layer < 4; ++layer) {
    float* ccopy = all_c + (size_t)layer * D;
    if (layer == 0) {
      // layer-0 cell reads f32 weights, side-writes fp8 copies
      lstm_cell_k<true, false><<<512, 256, 0, stream>>>(
          w_ih, w_hh, wih8, whh8, b_ih, b_hh, emb0,
          nullptr, nullptr, nullptr, nullptr, nullptr,
          hA, cA, ccopy, nullptr, nullptr, nullptr);
    } else {
      int ps = 2 * layer - 1;  // func-sample step of previous layer
      lstm_cell_k<false, true><<<512, 256, 0, stream>>>(
          wih8, whh8, nullptr, nullptr, b_ih, b_hh,
          embt + (size_t)(layer - 1) * V * D,
          part4, parti, logits, hB, cB,
          hA, cA, ccopy, out + ps, out + 9 + ps, out + 18 + ps);
    }
    float* cw = all_cw + (size_t)layer * D;
    if (layer == 0) {
      spec_lin_k<1, true><<<1536, 256, 0, stream>>>(
          wih8, whh8, b_ih, b_hh, hA, all_c,
          lin1_w, lin1_b, lin2_w, lin2_b, l18, l28,
          cA, g_ih, g_hh, cw, qb);
    } else {
      switch (layer) {
        case 1:  spec_lin_k<2, false><<<1536, 256, 0, stream>>>(wih8, whh8, b_ih, b_hh, hA, all_c, l18, lin1_b, l28, lin2_b, nullptr, nullptr, cA, g_ih, g_hh, cw, qb); break;
        case 2:  spec_lin_k<3, false><<<1536, 256, 0, stream>>>(wih8, whh8, b_ih, b_hh, hA, all_c, l18, lin1_b, l28, lin2_b, nullptr, nullptr, cA, g_ih, g_hh, cw, qb); break;
        default: spec_lin_k<4, false><<<1536, 256, 0, stream>>>(wih8, whh8, b_ih, b_hh, hA, all_c, l18, lin1_b, l28, lin2_b, nullptr, nullptr, cA, g_ih, g_hh, cw, qb); break;
      }
    }
    int step = 2 * layer;
    dec_fused_k<<<V / 4, 256, 0, stream>>>(dec_w + (size_t)layer * V * D,
                                           dec_b + (size_t)layer * V,
                                           g_ih, g_hh, cA, qb, all_cw, lin3_w, lin3_b,
                                           layer + 1, step, logits, hB, cB,
                                           out + step, out + 9 + step, out + 18 + step,
                                           part4, parti);
  }

  // final cell (consumes step-7 partials) + decode (step-8 partials) + reduce
  lstm_cell_k<false, true><<<512, 256, 0, stream>>>(
      wih8, whh8, nullptr, nullptr, b_ih, b_hh,
      embt + (size_t)3 * V * D, part4, parti, logits, hB, cB,
      hA, cA, nullptr, out + 7, out + 16, out + 25);
  gemv_k<<<V / 4, 256, 0, stream>>>(dec_w + (size_t)4 * V * D, dec_b + (size_t)4 * V,
                                    cA, logits, 8, part4, parti);
  reduce_sample_k<<<1, 256, 0, stream>>>(part4, parti, logits, out + 8, out + 17, out + 26);
}